// Round 2
// baseline (2469.454 us; speedup 1.0000x reference)
//
#include <hip/hip_runtime.h>

typedef unsigned short u16;
typedef __bf16 bf16x8 __attribute__((ext_vector_type(8)));
typedef float f32x4 __attribute__((ext_vector_type(4)));
typedef unsigned short u16x8 __attribute__((ext_vector_type(8)));

#define DEV __device__ __forceinline__

DEV u16 f2bf(float f) {
  union { float f; unsigned u; } a; a.f = f;
  unsigned r = a.u + 0x7fffu + ((a.u >> 16) & 1u);   // RNE
  return (u16)(r >> 16);
}
DEV float bf2f(u16 h) {
  union { unsigned u; float f; } a; a.u = ((unsigned)h) << 16;
  return a.f;
}
DEV void gload_lds16(const void* g, void* l) {
  __builtin_amdgcn_global_load_lds((const __attribute__((address_space(1))) void*)g,
                                   (__attribute__((address_space(3))) void*)l, 16, 0, 0);
}
// XOR swizzle on 16B-chunk index within a 256B row (8 chunks per 128B half)
DEV int swz(int row, int j) { return (j & 8) | ((j & 7) ^ (row & 7)); }

DEV f32x4 mfma16(bf16x8 a, bf16x8 b, f32x4 c) {
  return __builtin_amdgcn_mfma_f32_16x16x32_bf16(a, b, c, 0, 0, 0);
}

// ---------------------------------------------------------------- cast f32->bf16
__global__ __launch_bounds__(256) void castk(const float* __restrict__ in,
                                             u16* __restrict__ out, long n) {
  long i = ((long)blockIdx.x * 256 + threadIdx.x) * 8;
  const long stride = (long)gridDim.x * 256 * 8;
  for (; i < n; i += stride) {
    float4 v0 = *(const float4*)(in + i);
    float4 v1 = *(const float4*)(in + i + 4);
    u16x8 o;
    o[0] = f2bf(v0.x); o[1] = f2bf(v0.y); o[2] = f2bf(v0.z); o[3] = f2bf(v0.w);
    o[4] = f2bf(v1.x); o[5] = f2bf(v1.y); o[6] = f2bf(v1.z); o[7] = f2bf(v1.w);
    *(u16x8*)(out + i) = o;
  }
}

// ---------------------------------------------------------------- batched GEMM
// C = X @ W^T (+bias), X:[32768,2048] bf16, W:[2048,2048] bf16, out bf16 in
// head layout [B=256,H=16,L=128,DH=128]. Tile 128x128, BK=32, 4 waves (2x2 of 64x64).
// z: 0=q(X=qs) 1=k(X=ks) 2=v(X=vs) 3=g(X=qs)
__global__ __launch_bounds__(256, 2) void gemm4(
    const u16* __restrict__ qsb, const u16* __restrict__ ksb, const u16* __restrict__ vsb,
    const u16* __restrict__ Wb,
    const float* __restrict__ bq, const float* __restrict__ bk,
    const float* __restrict__ bv, const float* __restrict__ bg,
    u16* __restrict__ Hb) {
  __shared__ u16 Asm[128 * 32];
  __shared__ u16 Bsm[128 * 32];
  const int z = blockIdx.z;
  const u16* X = (z == 1) ? ksb : (z == 2) ? vsb : qsb;
  const u16* W = Wb + (size_t)z * 2048 * 2048;
  const float* bias = (z == 0) ? bq : (z == 1) ? bk : (z == 2) ? bv : bg;
  const int bi = blockIdx.y, bj = blockIdx.x;
  const int tid = threadIdx.x, lane = tid & 63, wid = tid >> 6;
  const int wr = wid >> 1, wc = wid & 1;
  const size_t K = 2048;
  const u16* Ab = X + (size_t)bi * 128 * K;
  const u16* Bb = W + (size_t)bj * 128 * K;
  const int srow = lane >> 2;          // row within 16-row staging chunk
  const int skof = (lane & 3) * 8;     // k element offset (16B per lane)
  f32x4 acc[4][4] = {};
  for (int k0 = 0; k0 < 2048; k0 += 32) {
    __syncthreads();
#pragma unroll
    for (int cc = 0; cc < 2; ++cc) {
      int c = wid * 2 + cc;            // 1024B LDS chunk id (16 rows of 64B)
      int row = c * 16 + srow;
      gload_lds16(Ab + (size_t)row * K + k0 + skof, (char*)Asm + c * 1024);
      gload_lds16(Bb + (size_t)row * K + k0 + skof, (char*)Bsm + c * 1024);
    }
    __syncthreads();
    bf16x8 af[4], bfv[4];
#pragma unroll
    for (int m = 0; m < 4; ++m)
      af[m] = *(const bf16x8*)&Asm[(wr * 64 + m * 16 + (lane & 15)) * 32 + (lane >> 4) * 8];
#pragma unroll
    for (int n = 0; n < 4; ++n)
      bfv[n] = *(const bf16x8*)&Bsm[(wc * 64 + n * 16 + (lane & 15)) * 32 + (lane >> 4) * 8];
#pragma unroll
    for (int m = 0; m < 4; ++m)
#pragma unroll
      for (int n = 0; n < 4; ++n)
        acc[m][n] = mfma16(af[m], bfv[n], acc[m][n]);
  }
  // epilogue: tile (bi,bj) == head tile (b=bi, h=bj); write bf16 head layout
  u16* O = Hb + (size_t)z * 67108864 + (size_t)(bi * 16 + bj) * 16384;
  const int cg = lane >> 4, cl = lane & 15;
  float bn[4];
#pragma unroll
  for (int n = 0; n < 4; ++n) bn[n] = bias[bj * 128 + wc * 64 + n * 16 + cl];
#pragma unroll
  for (int m = 0; m < 4; ++m)
#pragma unroll
    for (int n = 0; n < 4; ++n)
#pragma unroll
      for (int i = 0; i < 4; ++i) {
        int l = wr * 64 + m * 16 + cg * 4 + i;
        int d = wc * 64 + n * 16 + cl;
        O[l * 128 + d] = f2bf(acc[m][n][i] + bn[n]);
      }
}

// ---------------------------------------------------------------- attention per (b,h)
// S = (Q K^T)/sqrt(128) * sigmoid(Gpre); P = softmax_rows(S); ctx = P V.
// 4 waves; wave w owns S-rows w*32..w*32+31 (full 128 cols) -> row softmax is
// wave-local (16-lane butterflies). K, V^T, P live in swizzled LDS.
__global__ __launch_bounds__(256, 1) void attn(
    const u16* __restrict__ Qh, const u16* __restrict__ Kh, const u16* __restrict__ Vh,
    const u16* __restrict__ Gh, u16* __restrict__ Ch) {
  __shared__ u16 Ksm[128 * 128];       // K[lk][d], 16B chunks XOR-swizzled by row
  __shared__ u16 VTsm[128 * 128];      // V^T[d][lk], swizzled
  __shared__ u16 Psm[4 * 32 * 128];    // per-wave P[32][128] bf16, swizzled
  const int tid = threadIdx.x, lane = tid & 63, wid = tid >> 6;
  const size_t base = ((size_t)blockIdx.y * 16 + blockIdx.x) * 16384;
  const u16* Qg = Qh + base;
  const u16* Kg = Kh + base;
  const u16* Vg = Vh + base;
  const u16* Gg = Gh + base;
  u16* Cg = Ch + base;

  // --- stage K: linear LDS dest, inverse-swizzled global source (rule #21)
#pragma unroll
  for (int cc = 0; cc < 8; ++cc) {
    int c = wid * 8 + cc;              // 1024B chunk = 4 rows of 256B
    int row = c * 4 + (lane >> 4);
    int dc = lane & 15;                // 16B chunk within row
    gload_lds16(Kg + row * 128 + swz(row, dc) * 8, (char*)Ksm + c * 1024);
  }
  // --- stage V^T via register transpose, swizzled scatter writes
  {
    int lk = tid & 127;
    int dblk = tid >> 7;
#pragma unroll
    for (int dc8 = 0; dc8 < 8; ++dc8) {
      int d0 = dblk * 64 + dc8 * 8;
      u16x8 v = *(const u16x8*)(Vg + lk * 128 + d0);
#pragma unroll
      for (int e = 0; e < 8; ++e) {
        int d = d0 + e;
        int byt = d * 256 + swz(d, lk >> 3) * 16 + (lk & 7) * 2;
        *(u16*)((char*)VTsm + byt) = v[e];
      }
    }
  }
  // --- Q fragments straight from global (each wave reads its own 32 rows)
  bf16x8 qf[2][4];
#pragma unroll
  for (int m = 0; m < 2; ++m)
#pragma unroll
    for (int kk = 0; kk < 4; ++kk)
      qf[m][kk] = *(const bf16x8*)(Qg + (wid * 32 + m * 16 + (lane & 15)) * 128 +
                                   kk * 32 + (lane >> 4) * 8);
  __syncthreads();

  // --- QK^T : rows (m=0,1), cols (n=0..7), K-dim = d (4 steps of 32)
  f32x4 s[2][8] = {};
#pragma unroll
  for (int kk = 0; kk < 4; ++kk) {
    bf16x8 kf[8];
#pragma unroll
    for (int n = 0; n < 8; ++n) {
      int row = n * 16 + (lane & 15);
      int j = kk * 4 + (lane >> 4);
      kf[n] = *(const bf16x8*)((const char*)Ksm + row * 256 + swz(row, j) * 16);
    }
#pragma unroll
    for (int m = 0; m < 2; ++m)
#pragma unroll
      for (int n = 0; n < 8; ++n)
        s[m][n] = mfma16(qf[m][kk], kf[n], s[m][n]);
  }

  // --- gate + row softmax (rows are wave-local; reduce over 16 col-lanes)
  const float scale = 0.08838834764831843f;  // 1/sqrt(128)
  float pmax[2][4], psum[2][4];
#pragma unroll
  for (int m = 0; m < 2; ++m)
#pragma unroll
    for (int i = 0; i < 4; ++i) pmax[m][i] = -1e30f;
#pragma unroll
  for (int m = 0; m < 2; ++m)
#pragma unroll
    for (int n = 0; n < 8; ++n)
#pragma unroll
      for (int i = 0; i < 4; ++i) {
        int l = wid * 32 + m * 16 + (lane >> 4) * 4 + i;
        int lk = n * 16 + (lane & 15);
        float gp = bf2f(Gg[l * 128 + lk]);
        float gate = 1.0f / (1.0f + __expf(-gp));
        float val = s[m][n][i] * scale * gate;
        s[m][n][i] = val;
        pmax[m][i] = fmaxf(pmax[m][i], val);
      }
#pragma unroll
  for (int m = 0; m < 2; ++m)
#pragma unroll
    for (int i = 0; i < 4; ++i) {
      float v = pmax[m][i];
      v = fmaxf(v, __shfl_xor(v, 1));
      v = fmaxf(v, __shfl_xor(v, 2));
      v = fmaxf(v, __shfl_xor(v, 4));
      v = fmaxf(v, __shfl_xor(v, 8));
      pmax[m][i] = v;
      psum[m][i] = 0.f;
    }
#pragma unroll
  for (int m = 0; m < 2; ++m)
#pragma unroll
    for (int n = 0; n < 8; ++n)
#pragma unroll
      for (int i = 0; i < 4; ++i) {
        float p = __expf(s[m][n][i] - pmax[m][i]);
        s[m][n][i] = p;
        psum[m][i] += p;
      }
#pragma unroll
  for (int m = 0; m < 2; ++m)
#pragma unroll
    for (int i = 0; i < 4; ++i) {
      float v = psum[m][i];
      v += __shfl_xor(v, 1);
      v += __shfl_xor(v, 2);
      v += __shfl_xor(v, 4);
      v += __shfl_xor(v, 8);
      psum[m][i] = 1.0f / v;               // normalize after PV
    }
  // --- P (unnormalized, in [0,1]) -> LDS bf16, swizzled
#pragma unroll
  for (int m = 0; m < 2; ++m)
#pragma unroll
    for (int n = 0; n < 8; ++n)
#pragma unroll
      for (int i = 0; i < 4; ++i) {
        int r = m * 16 + (lane >> 4) * 4 + i;
        int lk = n * 16 + (lane & 15);
        int byt = wid * 8192 + r * 256 + swz(r, lk >> 3) * 16 + (lk & 7) * 2;
        *(u16*)((char*)Psm + byt) = f2bf(s[m][n][i]);
      }
  __syncthreads();

  // --- PV : out rows (m), cols d (n=0..7), K-dim = lk (4 steps of 32)
  f32x4 o[2][8] = {};
#pragma unroll
  for (int kk = 0; kk < 4; ++kk) {
    bf16x8 pf[2], vf[8];
#pragma unroll
    for (int m = 0; m < 2; ++m) {
      int r = m * 16 + (lane & 15);
      int j = kk * 4 + (lane >> 4);
      pf[m] = *(const bf16x8*)((const char*)Psm + wid * 8192 + r * 256 + swz(r, j) * 16);
    }
#pragma unroll
    for (int n = 0; n < 8; ++n) {
      int d = n * 16 + (lane & 15);
      int j = kk * 4 + (lane >> 4);
      vf[n] = *(const bf16x8*)((const char*)VTsm + d * 256 + swz(d, j) * 16);
    }
#pragma unroll
    for (int m = 0; m < 2; ++m)
#pragma unroll
      for (int n = 0; n < 8; ++n)
        o[m][n] = mfma16(pf[m], vf[n], o[m][n]);
  }
  // --- epilogue: ctx bf16 head layout, normalized
#pragma unroll
  for (int m = 0; m < 2; ++m)
#pragma unroll
    for (int n = 0; n < 8; ++n)
#pragma unroll
      for (int i = 0; i < 4; ++i) {
        int l = wid * 32 + m * 16 + (lane >> 4) * 4 + i;
        int d = n * 16 + (lane & 15);
        Cg[l * 128 + d] = f2bf(o[m][n][i] * psum[m][i]);
      }
}

// ---------------------------------------------------------------- residual + LayerNorm
// one block per (b,l) row of 2048; gather ctx across heads, add value_states, LN.
__global__ __launch_bounds__(256) void resid_ln(
    const u16* __restrict__ Ch, const float* __restrict__ vsf,
    const float* __restrict__ gamma, const float* __restrict__ beta,
    float* __restrict__ out) {
  const int rid = blockIdx.x;            // 0..32767
  const int b = rid >> 7, l = rid & 127;
  const int t = threadIdx.x, lane = t & 63, wid = t >> 6;
  const int h = t >> 4, d0 = (t & 15) * 8;   // j0 = t*8 = h*128 + d0
  const u16x8 cv = *(const u16x8*)(Ch + ((size_t)(b * 16 + h) * 128 + l) * 128 + d0);
  const float* vp = vsf + (size_t)rid * 2048 + t * 8;
  float4 v0 = *(const float4*)vp;
  float4 v1 = *(const float4*)(vp + 4);
  float x[8];
  x[0] = bf2f(cv[0]) + v0.x; x[1] = bf2f(cv[1]) + v0.y;
  x[2] = bf2f(cv[2]) + v0.z; x[3] = bf2f(cv[3]) + v0.w;
  x[4] = bf2f(cv[4]) + v1.x; x[5] = bf2f(cv[5]) + v1.y;
  x[6] = bf2f(cv[6]) + v1.z; x[7] = bf2f(cv[7]) + v1.w;
  float sum = 0.f, sq = 0.f;
#pragma unroll
  for (int e = 0; e < 8; ++e) { sum += x[e]; sq += x[e] * x[e]; }
#pragma unroll
  for (int mask = 1; mask < 64; mask <<= 1) {
    sum += __shfl_xor(sum, mask);
    sq  += __shfl_xor(sq, mask);
  }
  __shared__ float red[8];
  if (lane == 0) { red[wid] = sum; red[4 + wid] = sq; }
  __syncthreads();
  sum = red[0] + red[1] + red[2] + red[3];
  sq  = red[4] + red[5] + red[6] + red[7];
  const float mu = sum * (1.0f / 2048.0f);
  const float var = sq * (1.0f / 2048.0f) - mu * mu;
  const float rs = rsqrtf(var + 1e-6f);
  const int j0 = t * 8;
  float4 g0 = *(const float4*)(gamma + j0), g1 = *(const float4*)(gamma + j0 + 4);
  float4 be0 = *(const float4*)(beta + j0), be1 = *(const float4*)(beta + j0 + 4);
  float4 o0, o1;
  o0.x = (x[0] - mu) * rs * g0.x + be0.x;
  o0.y = (x[1] - mu) * rs * g0.y + be0.y;
  o0.z = (x[2] - mu) * rs * g0.z + be0.z;
  o0.w = (x[3] - mu) * rs * g0.w + be0.w;
  o1.x = (x[4] - mu) * rs * g1.x + be1.x;
  o1.y = (x[5] - mu) * rs * g1.y + be1.y;
  o1.z = (x[6] - mu) * rs * g1.z + be1.z;
  o1.w = (x[7] - mu) * rs * g1.w + be1.w;
  float* op = out + (size_t)rid * 2048 + j0;
  *(float4*)op = o0;
  *(float4*)(op + 4) = o1;
}

// ---------------------------------------------------------------- launch
extern "C" void kernel_launch(void* const* d_in, const int* in_sizes, int n_in,
                              void* d_out, int out_size, void* d_ws, size_t ws_size,
                              hipStream_t stream) {
  const float* qs = (const float*)d_in[0];
  const float* ks = (const float*)d_in[1];
  const float* vs = (const float*)d_in[2];
  const float* Wq = (const float*)d_in[3];
  const float* bq = (const float*)d_in[4];
  const float* Wk = (const float*)d_in[5];
  const float* bk = (const float*)d_in[6];
  const float* Wv = (const float*)d_in[7];
  const float* bv = (const float*)d_in[8];
  const float* Wg = (const float*)d_in[9];
  const float* bg = (const float*)d_in[10];
  const float* gamma = (const float*)d_in[11];
  const float* beta  = (const float*)d_in[12];
  float* out = (float*)d_out;

  char* ws = (char*)d_ws;
  const size_t S1 = (size_t)32768 * 2048 * 2;   // 134,217,728 B per bf16 state
  const size_t WSZ = (size_t)4 * 2048 * 2048 * 2;
  u16* qsb = (u16*)(ws);
  u16* ksb = (u16*)(ws + S1);
  u16* vsb = (u16*)(ws + 2 * S1);
  u16* Wb  = (u16*)(ws + 3 * S1);
  u16* Hb  = (u16*)(ws + 3 * S1 + WSZ);         // q,k,v,g head tensors (bf16)
  u16* ctx = qsb;                               // reuse qs_bf after GEMMs
  // total ws need: 7*S1 + WSZ = 973,078,528 B

  const long NS = 67108864, NW = 4194304;
  castk<<<2048, 256, 0, stream>>>(qs, qsb, NS);
  castk<<<2048, 256, 0, stream>>>(ks, ksb, NS);
  castk<<<2048, 256, 0, stream>>>(vs, vsb, NS);
  castk<<<512, 256, 0, stream>>>(Wq, Wb, NW);
  castk<<<512, 256, 0, stream>>>(Wk, Wb + NW, NW);
  castk<<<512, 256, 0, stream>>>(Wv, Wb + 2 * NW, NW);
  castk<<<512, 256, 0, stream>>>(Wg, Wb + 3 * NW, NW);

  gemm4<<<dim3(16, 256, 4), 256, 0, stream>>>(qsb, ksb, vsb, Wb, bq, bk, bv, bg, Hb);

  attn<<<dim3(16, 256), 256, 0, stream>>>(Hb, Hb + NS, Hb + 2 * NS, Hb + 3 * NS, ctx);

  resid_ln<<<32768, 256, 0, stream>>>(ctx, vs, gamma, beta, out);
}